// Round 11
// baseline (139.623 us; speedup 1.0000x reference)
//
#include <hip/hip_runtime.h>
#include <hip/hip_bf16.h>

// DenseGraphSimpleOpEdgeFlow: out[b,i,f] = sum_j attn[b,i,j,f]*support[b,j,f] + support[b,i,f]
//   support = inputs @ weight  (fp32)
//   attn = mask(sigmoid(op_emb' @ attn_w + attn_b)); diagonal op_emb replaced by self_op_emb,
//   adj' = adj + I; adj'==0 -> 0, adj'==1 (SKIP) -> 1, else sigmoid.
// R11: dispatch-rate fix. Measured WG dispatch ~45-73 WG/us explains every round's occupancy
// (R1 41%, R5 21%, R10 41% all predicted by rate*lifetime/256CU): 6144-block grids are
// CP-starved to ~3 blocks/CU; small grids ramp too slowly to ever co-reside. This round:
// 512 blocks x 1024 threads (16 waves), dispatched in ~9us, resident for the whole kernel.
// Waves are fully independent (R5's proven no-LDS no-barrier body): each wave does 3
// consecutive (b,i) tiles of the same b -> bfrag AND sfrag hoisted out of the tile loop.
// Mask = per-element addend off[adj'] (+126 -> attn 0, -126 -> attn 1 via exp2 saturation);
// diagonal exact via self_op substitution in the A-load. attn = rcp(1+exp2(acc+off)).
// Requires ws_size >= 64*96*128*4 = 3,145,728 bytes (S2 fragment-layout support scratch).

#define B_ 64
#define N_ 96
#define F_ 128
#define D_ 48

typedef __attribute__((ext_vector_type(8))) short short8;
typedef __attribute__((ext_vector_type(4))) float f32x4;

#if __has_builtin(__builtin_amdgcn_exp2f)
#define EXP2(x) __builtin_amdgcn_exp2f(x)
#else
#define EXP2(x) exp2f(x)
#endif

// S2 fragment layout: float2 index (((b*4 + lg)*64 + fbp)*6 + mt)*4 + r
__device__ __forceinline__ size_t s2idx(int b, int lg, int fbp, int mt, int r) {
    return ((((size_t)b * 4 + lg) * 64 + fbp) * 6 + mt) * 4 + r;
}

__device__ __forceinline__ unsigned bfbits(float x) {
    union { __hip_bfloat16 h; unsigned short u; } cv;
    cv.h = __float2bfloat16(x);
    return (unsigned)cv.u;
}

// ---------------- Kernel 1: support = inputs @ weight, written in fragment layout ----------------
__global__ __launch_bounds__(256, 4) void support_kernel(
    const float* __restrict__ inputs, const float* __restrict__ weight,
    float2* __restrict__ S2)
{
    __shared__ float in_lds[16 * F_];
    const int tid = threadIdx.x;
    const int row0 = blockIdx.x * 16;
    ((float4*)in_lds)[tid]       = ((const float4*)(inputs + (size_t)row0 * F_))[tid];
    ((float4*)in_lds)[tid + 256] = ((const float4*)(inputs + (size_t)row0 * F_))[tid + 256];
    __syncthreads();
    const int rl = tid >> 4, f0 = (tid & 15) * 8;
    float acc[8] = {0.f,0.f,0.f,0.f,0.f,0.f,0.f,0.f};
    #pragma unroll 4
    for (int k = 0; k < F_; ++k) {
        const float a = in_lds[rl * F_ + k];
        const float4 w0 = *(const float4*)(weight + k * F_ + f0);
        const float4 w1 = *(const float4*)(weight + k * F_ + f0 + 4);
        acc[0] += a * w0.x; acc[1] += a * w0.y; acc[2] += a * w0.z; acc[3] += a * w0.w;
        acc[4] += a * w1.x; acc[5] += a * w1.y; acc[6] += a * w1.z; acc[7] += a * w1.w;
    }
    const int R = row0 + rl;
    const int b = R / N_, j = R - b * N_;
    const int mt = j >> 4, lg = (j >> 2) & 3, r = j & 3;
    #pragma unroll
    for (int q = 0; q < 4; ++q) {
        const int fbp = (f0 >> 1) + q;   // f-pair index
        S2[s2idx(b, lg, fbp, mt, r)] = make_float2(acc[2 * q], acc[2 * q + 1]);
    }
}

// ---------------- Kernel 2: fused attn-GEMM + mask + weighted reduce + residual ----------------
// 512 blocks x 1024 threads = 16 waves; wave (quad,wvq) independently computes 3 tiles.
// Within a tile, wave wvq owns f = wvq*32 + (lane&15)*2 + t. MFMA 16x16x32 k-slot fill
// d = ks*32 + (lane>>4)*8 + e, identical for A and B (physical-k permutation cancels).
// C/D (HW-verified): col = lane&15 (-> f-pair), row = (lane>>4)*4 + reg (-> j).
__global__ __launch_bounds__(1024, 4) void fused_kernel(
    const float* __restrict__ op_emb,
    const unsigned* __restrict__ adjw,      // raw 32-bit view of adj (int32 or int64)
    const float* __restrict__ attn_w,
    const float* __restrict__ attn_b,
    const float* __restrict__ self_op,
    const float2* __restrict__ S2,
    float* __restrict__ out)
{
    const int tid  = threadIdx.x;
    const int lane = tid & 63;
    const int wvq  = (tid >> 6) & 3;   // wave within quad -> f-slice
    const int quad = tid >> 8;         // quad 0..3
    const int lg   = lane >> 4;        // k-slot group / j-subgroup 0..3
    const int lm   = lane & 15;
    const int fb   = wvq * 32 + lm * 2;   // f-pair base
    const int fbp  = wvq * 16 + lm;       // f-pair index

    const int gt0 = blockIdx.x * 12 + quad * 3;   // first of 3 consecutive tiles, same b
    const int b   = gt0 / N_;
    const int i0  = gt0 - b * N_;

    const float kNL2E = -1.44269504088896f;   // -log2(e)

    // --- adj dtype sniff: int64 little-endian has all-zero high words (values 0..4) ---
    const unsigned probe = adjw[2 * lane + 1];
    const bool use32 = __any(probe != 0);

    // --- B fragments (attn_w pre-scaled by -log2e; d>=48 -> 0) + bias: once per wave ---
    short8 bfrag[2][2];     // [t][ks]
    float  bbias[2];
    {
        const float2 bb = *(const float2*)(attn_b + fb);
        bbias[0] = bb.x * kNL2E;
        bbias[1] = bb.y * kNL2E;
        #pragma unroll
        for (int ks = 0; ks < 2; ++ks) {
            short8 v0, v1;
            #pragma unroll
            for (int e = 0; e < 8; ++e) {
                const int d = ks * 32 + lg * 8 + e;
                if (d < D_) {
                    const float2 w = *(const float2*)(attn_w + d * F_ + fb);
                    v0[e] = (short)bfbits(w.x * kNL2E);
                    v1[e] = (short)bfbits(w.y * kNL2E);
                } else {
                    v0[e] = 0; v1[e] = 0;
                }
            }
            bfrag[0][ks] = v0;
            bfrag[1][ks] = v1;
        }
    }

    // --- support fragments: 12 contiguous dwordx4, b-invariant across the 3 tiles ---
    float2 sfrag[6][4];
    {
        const float4* sp = (const float4*)(S2 + s2idx(b, lg, fbp, 0, 0));
        #pragma unroll
        for (int q = 0; q < 12; ++q) {
            const float4 v = sp[q];
            sfrag[(2 * q) / 4][(2 * q) & 3]         = make_float2(v.x, v.y);
            sfrag[(2 * q + 1) / 4][(2 * q + 1) & 3] = make_float2(v.z, v.w);
        }
    }

    #pragma unroll 1
    for (int t = 0; t < 3; ++t) {
        const int i = i0 + t;
        const size_t rb = (size_t)(b * N_ + i) * N_;
        const float* arow = op_emb + rb * D_;

        float osum0 = 0.f, osum1 = 0.f;
        #pragma unroll
        for (int mt = 0; mt < 6; ++mt) {
            // adj' codes for epilogue j = mt*16 + lg*4 + r (vector load, lane-local)
            int araw[4];
            {
                const size_t j0 = (size_t)mt * 16 + lg * 4;
                if (use32) {
                    const uint4 v = *(const uint4*)(adjw + rb + j0);
                    araw[0] = (int)v.x; araw[1] = (int)v.y; araw[2] = (int)v.z; araw[3] = (int)v.w;
                } else {
                    const uint4 v0 = *(const uint4*)(adjw + 2 * (rb + j0));
                    const uint4 v1 = *(const uint4*)(adjw + 2 * (rb + j0) + 4);
                    araw[0] = (int)v0.x; araw[1] = (int)v0.z; araw[2] = (int)v1.x; araw[3] = (int)v1.z;
                }
                #pragma unroll
                for (int r = 0; r < 4; ++r)
                    araw[r] += ((int)j0 + r == i) ? 1 : 0;
            }
            // A fragments: lane (lg,lm) reads 8 contiguous floats of row j = mt*16+lm;
            // row i substituted by self_op (diagonal), k-pad d in [48,64) = 0.
            const int jrow = mt * 16 + lm;
            const float* rp = (jrow == i) ? self_op : (arow + (size_t)jrow * D_);
            const float4 fa0 = *(const float4*)(rp + lg * 8);
            const float4 fa1 = *(const float4*)(rp + lg * 8 + 4);
            float4 fb0 = make_float4(0.f, 0.f, 0.f, 0.f), fb1 = fb0;
            if (lg < 2) {                 // ks1 covers d in [32,48); lg>=2 is the zero pad
                fb0 = *(const float4*)(rp + 32 + lg * 8);
                fb1 = *(const float4*)(rp + 32 + lg * 8 + 4);
            }
            short8 a0, a1;
            a0[0] = (short)bfbits(fa0.x); a0[1] = (short)bfbits(fa0.y);
            a0[2] = (short)bfbits(fa0.z); a0[3] = (short)bfbits(fa0.w);
            a0[4] = (short)bfbits(fa1.x); a0[5] = (short)bfbits(fa1.y);
            a0[6] = (short)bfbits(fa1.z); a0[7] = (short)bfbits(fa1.w);
            a1[0] = (short)bfbits(fb0.x); a1[1] = (short)bfbits(fb0.y);
            a1[2] = (short)bfbits(fb0.z); a1[3] = (short)bfbits(fb0.w);
            a1[4] = (short)bfbits(fb1.x); a1[5] = (short)bfbits(fb1.y);
            a1[6] = (short)bfbits(fb1.z); a1[7] = (short)bfbits(fb1.w);

            f32x4 c0 = (f32x4){bbias[0], bbias[0], bbias[0], bbias[0]};
            f32x4 c1 = (f32x4){bbias[1], bbias[1], bbias[1], bbias[1]};
            c0 = __builtin_amdgcn_mfma_f32_16x16x32_bf16(a0, bfrag[0][0], c0, 0, 0, 0);
            c0 = __builtin_amdgcn_mfma_f32_16x16x32_bf16(a1, bfrag[0][1], c0, 0, 0, 0);
            c1 = __builtin_amdgcn_mfma_f32_16x16x32_bf16(a0, bfrag[1][0], c1, 0, 0, 0);
            c1 = __builtin_amdgcn_mfma_f32_16x16x32_bf16(a1, bfrag[1][1], c1, 0, 0, 0);

            // attn = rcp(1 + exp2(acc + off)); off: a'==0 -> +126 (attn 0), a'==1 -> -126
            // (attn 1), else 0 (plain sigmoid). Saturation of exp2 encodes the mask.
            #pragma unroll
            for (int r = 0; r < 4; ++r) {
                const int a = araw[r];
                const float off = (a == 0) ? 126.f : ((a == 1) ? -126.f : 0.f);
                const float s0 = __builtin_amdgcn_rcpf(1.f + EXP2(c0[r] + off));
                const float s1 = __builtin_amdgcn_rcpf(1.f + EXP2(c1[r] + off));
                osum0 = __builtin_fmaf(s0, sfrag[mt][r].x, osum0);
                osum1 = __builtin_fmaf(s1, sfrag[mt][r].y, osum1);
            }
        }

        // reduce over the 4 lg j-subsets; lanes 0..15 add residual and store the f-pair
        osum0 += __shfl_xor(osum0, 16);
        osum0 += __shfl_xor(osum0, 32);
        osum1 += __shfl_xor(osum1, 16);
        osum1 += __shfl_xor(osum1, 32);
        if (lg == 0) {
            const float2 sr = S2[s2idx(b, (i >> 2) & 3, fbp, i >> 4, i & 3)];
            float2 o;
            o.x = osum0 + sr.x;
            o.y = osum1 + sr.y;
            *(float2*)(out + (size_t)(b * N_ + i) * F_ + fb) = o;
        }
    }
}

extern "C" void kernel_launch(void* const* d_in, const int* in_sizes, int n_in,
                              void* d_out, int out_size, void* d_ws, size_t ws_size,
                              hipStream_t stream) {
    const float*    inputs  = (const float*)d_in[0];
    const unsigned* adjw    = (const unsigned*)d_in[1];
    const float*    op_emb  = (const float*)d_in[2];
    const float*    weight  = (const float*)d_in[3];
    const float*    attn_w  = (const float*)d_in[4];
    const float*    attn_b  = (const float*)d_in[5];
    const float*    self_op = (const float*)d_in[6];
    float* out = (float*)d_out;
    float2* S2 = (float2*)d_ws;  // fragment-layout support, 3,145,728 bytes

    support_kernel<<<(B_ * N_) / 16, 256, 0, stream>>>(inputs, weight, S2);
    fused_kernel<<<512, 1024, 0, stream>>>(op_emb, adjw, attn_w, attn_b, self_op,
                                           S2, out);
}

// Round 12
// 126.572 us; speedup vs baseline: 1.1031x; 1.1031x over previous
//
#include <hip/hip_runtime.h>
#include <hip/hip_bf16.h>

// DenseGraphSimpleOpEdgeFlow — R12: ABLATION ROUND (R10 base, best profiled 84.8us).
// Three structural theories (async-split R4, no-barrier R5, fat-resident R11) all failed to
// move the ~84us wall; per skill Common-mistake #8, this round measures instead of guessing.
// V1 (fused_probe) = R10 fused with the 113-MB op_emb stream replaced by L1-resident attn_w
// reads (same instruction structure, no stream); writes out (overwritten). V0 (fused_kernel)
// = R10 verbatim, launched last (correct output). rocprof per-dispatch dur_us + bench total
// separate V0 vs V1:  V1≈V0 -> structure/latency-bound;  V1<<V0 -> memory-stream-bound.
// Requires ws_size >= 64*96*128*4 = 3,145,728 bytes (S2 fragment-layout support scratch).

#define B_ 64
#define N_ 96
#define F_ 128
#define D_ 48

typedef __attribute__((ext_vector_type(8))) short short8;
typedef __attribute__((ext_vector_type(4))) float f32x4;

#if __has_builtin(__builtin_amdgcn_exp2f)
#define EXP2(x) __builtin_amdgcn_exp2f(x)
#else
#define EXP2(x) exp2f(x)
#endif

// S2 fragment layout: float2 index (((b*4 + lg)*64 + fbp)*6 + mt)*4 + r
__device__ __forceinline__ size_t s2idx(int b, int lg, int fbp, int mt, int r) {
    return ((((size_t)b * 4 + lg) * 64 + fbp) * 6 + mt) * 4 + r;
}

__device__ __forceinline__ unsigned bfbits(float x) {
    union { __hip_bfloat16 h; unsigned short u; } cv;
    cv.h = __float2bfloat16(x);
    return (unsigned)cv.u;
}

// ---------------- Kernel 1: support = inputs @ weight, written in fragment layout ----------------
__global__ __launch_bounds__(256, 4) void support_kernel(
    const float* __restrict__ inputs, const float* __restrict__ weight,
    float2* __restrict__ S2)
{
    __shared__ float in_lds[16 * F_];
    const int tid = threadIdx.x;
    const int row0 = blockIdx.x * 16;
    ((float4*)in_lds)[tid]       = ((const float4*)(inputs + (size_t)row0 * F_))[tid];
    ((float4*)in_lds)[tid + 256] = ((const float4*)(inputs + (size_t)row0 * F_))[tid + 256];
    __syncthreads();
    const int rl = tid >> 4, f0 = (tid & 15) * 8;
    float acc[8] = {0.f,0.f,0.f,0.f,0.f,0.f,0.f,0.f};
    #pragma unroll 4
    for (int k = 0; k < F_; ++k) {
        const float a = in_lds[rl * F_ + k];
        const float4 w0 = *(const float4*)(weight + k * F_ + f0);
        const float4 w1 = *(const float4*)(weight + k * F_ + f0 + 4);
        acc[0] += a * w0.x; acc[1] += a * w0.y; acc[2] += a * w0.z; acc[3] += a * w0.w;
        acc[4] += a * w1.x; acc[5] += a * w1.y; acc[6] += a * w1.z; acc[7] += a * w1.w;
    }
    const int R = row0 + rl;
    const int b = R / N_, j = R - b * N_;
    const int mt = j >> 4, lg = (j >> 2) & 3, r = j & 3;
    #pragma unroll
    for (int q = 0; q < 4; ++q) {
        const int fbp = (f0 >> 1) + q;   // f-pair index
        S2[s2idx(b, lg, fbp, mt, r)] = make_float2(acc[2 * q], acc[2 * q + 1]);
    }
}

// ---------------- fused body, shared by V0 (real) and V1 (probe) ----------------
// One block per (b,i); 4 waves; wave w owns f = w*32 + (lane&15)*2 + t.
// PROBE==1 replaces op_emb staging reads with L1-resident attn_w reads (same structure).
template <int PROBE>
__device__ __forceinline__ void fused_body(
    const float* __restrict__ op_emb,
    const unsigned* __restrict__ adjw,
    const float* __restrict__ attn_w,
    const float* __restrict__ attn_b,
    const float* __restrict__ self_op,
    const float2* __restrict__ S2,
    float* __restrict__ out)
{
    __shared__ __align__(16) unsigned short Atile[N_ * 64];  // 12 KB; d=48 is the mask slot

    const int tid  = threadIdx.x;
    const int lane = tid & 63;
    const int wv   = tid >> 6;
    const int lg   = lane >> 4;
    const int lm   = lane & 15;
    const int fb   = wv * 32 + lm * 2;
    const int fbp  = wv * 16 + lm;

    const int blk = blockIdx.x;
    const int b   = blk / N_;
    const int i   = blk - b * N_;
    const size_t rb = (size_t)(b * N_ + i) * N_;
    const float* src = op_emb + rb * D_;

    const float kNL2E = -1.44269504088896f;

    const unsigned probe = adjw[2 * lane + 1];
    const bool use32 = __any(probe != 0);

    // ---- staging loads issue first ----
    float4 ld[5];
    #pragma unroll
    for (int s = 0; s < 5; ++s) {
        const int w = tid + s * 256;
        if (w < N_ * 12) {
            const int j = w / 12, c = w - 12 * j;
            if (PROBE) {
                ld[s] = (j == i) ? *(const float4*)(self_op + c * 4)
                                 : *(const float4*)(attn_w + ((4 * w) & 4095));
            } else {
                ld[s] = (j == i) ? *(const float4*)(self_op + c * 4)
                                 : *(const float4*)(src + (size_t)j * D_ + c * 4);
            }
        }
    }
    int araw = 0;
    if (tid < N_) {
        const size_t idx = rb + tid;
        araw = use32 ? (int)adjw[idx] : (int)adjw[2 * idx];
        araw += (tid == i) ? 1 : 0;
    }

    // --- B fragments + bias ---
    short8 bfrag[2][2];
    float  bbias[2];
    {
        const float2 bb = *(const float2*)(attn_b + fb);
        bbias[0] = bb.x * kNL2E;
        bbias[1] = bb.y * kNL2E;
        #pragma unroll
        for (int ks = 0; ks < 2; ++ks) {
            short8 v0, v1;
            #pragma unroll
            for (int e = 0; e < 8; ++e) {
                const int d = ks * 32 + lg * 8 + e;
                if (d < D_) {
                    const float2 w = *(const float2*)(attn_w + d * F_ + fb);
                    v0[e] = (short)bfbits(w.x * kNL2E);
                    v1[e] = (short)bfbits(w.y * kNL2E);
                } else {
                    const unsigned one = (d == D_) ? bfbits(1.0f) : 0u;
                    v0[e] = (short)one;
                    v1[e] = (short)one;
                }
            }
            bfrag[0][ks] = v0;
            bfrag[1][ks] = v1;
        }
    }

    // --- support fragments: 12 contiguous dwordx4 ---
    float2 sfrag[6][4];
    {
        const float4* sp = (const float4*)(S2 + s2idx(b, lg, fbp, 0, 0));
        #pragma unroll
        for (int q = 0; q < 12; ++q) {
            const float4 v = sp[q];
            sfrag[(2 * q) / 4][(2 * q) & 3]         = make_float2(v.x, v.y);
            sfrag[(2 * q + 1) / 4][(2 * q + 1) & 3] = make_float2(v.z, v.w);
        }
    }

    // --- zero the k-pad d in [50,64) ---
    for (int v = tid; v < N_ * 7; v += 256) {
        const int j = v / 7, q = v - 7 * j;
        const int byte = j * 128 + ((100 + q * 4) ^ ((j & 7) << 4));
        *(unsigned*)((char*)Atile + byte) = 0u;
    }

    // ---- stage to LDS (XOR-swizzled); d48 <- off_j mask slot ----
    #pragma unroll
    for (int s = 0; s < 5; ++s) {
        const int w = tid + s * 256;
        if (w < N_ * 12) {
            const int j = w / 12, c = w - 12 * j;
            const int byte = j * 128 + ((c * 8) ^ ((j & 7) << 4));
            *(uint2*)((char*)Atile + byte) =
                make_uint2(bfbits(ld[s].x) | (bfbits(ld[s].y) << 16),
                           bfbits(ld[s].z) | (bfbits(ld[s].w) << 16));
        }
    }
    if (tid < N_) {
        const float off = (araw == 0) ? 126.f : ((araw == 1) ? -126.f : 0.f);
        const int byte = tid * 128 + (96 ^ ((tid & 7) << 4));
        *(unsigned*)((char*)Atile + byte) = bfbits(off);
    }
    __syncthreads();

    // ---- compute ----
    float osum0 = 0.f, osum1 = 0.f;
    #pragma unroll
    for (int mt = 0; mt < 6; ++mt) {
        const int jr  = mt * 16 + lm;
        const int swz = (lm & 7) << 4;
        const char* base = (const char*)Atile + jr * 128;
        const short8 a0 = *(const short8*)(base + (( 0 + lg * 16) ^ swz));
        const short8 a1 = *(const short8*)(base + ((64 + lg * 16) ^ swz));
        f32x4 c0 = (f32x4){bbias[0], bbias[0], bbias[0], bbias[0]};
        f32x4 c1 = (f32x4){bbias[1], bbias[1], bbias[1], bbias[1]};
        c0 = __builtin_amdgcn_mfma_f32_16x16x32_bf16(a0, bfrag[0][0], c0, 0, 0, 0);
        c0 = __builtin_amdgcn_mfma_f32_16x16x32_bf16(a1, bfrag[0][1], c0, 0, 0, 0);
        c1 = __builtin_amdgcn_mfma_f32_16x16x32_bf16(a0, bfrag[1][0], c1, 0, 0, 0);
        c1 = __builtin_amdgcn_mfma_f32_16x16x32_bf16(a1, bfrag[1][1], c1, 0, 0, 0);
        #pragma unroll
        for (int r = 0; r < 4; ++r) {
            const float s0 = __builtin_amdgcn_rcpf(1.f + EXP2(c0[r]));
            const float s1 = __builtin_amdgcn_rcpf(1.f + EXP2(c1[r]));
            osum0 = __builtin_fmaf(s0, sfrag[mt][r].x, osum0);
            osum1 = __builtin_fmaf(s1, sfrag[mt][r].y, osum1);
        }
    }

    osum0 += __shfl_xor(osum0, 16);
    osum0 += __shfl_xor(osum0, 32);
    osum1 += __shfl_xor(osum1, 16);
    osum1 += __shfl_xor(osum1, 32);
    if (lg == 0) {
        const float2 sr = S2[s2idx(b, (i >> 2) & 3, fbp, i >> 4, i & 3)];
        float2 o;
        o.x = osum0 + sr.x;
        o.y = osum1 + sr.y;
        *(float2*)(out + (size_t)(b * N_ + i) * F_ + fb) = o;
    }
}

__global__ __launch_bounds__(256, 2) void fused_probe(
    const float* __restrict__ op_emb, const unsigned* __restrict__ adjw,
    const float* __restrict__ attn_w, const float* __restrict__ attn_b,
    const float* __restrict__ self_op, const float2* __restrict__ S2,
    float* __restrict__ out)
{
    fused_body<1>(op_emb, adjw, attn_w, attn_b, self_op, S2, out);
}

__global__ __launch_bounds__(256, 2) void fused_kernel(
    const float* __restrict__ op_emb, const unsigned* __restrict__ adjw,
    const float* __restrict__ attn_w, const float* __restrict__ attn_b,
    const float* __restrict__ self_op, const float2* __restrict__ S2,
    float* __restrict__ out)
{
    fused_body<0>(op_emb, adjw, attn_w, attn_b, self_op, S2, out);
}

extern "C" void kernel_launch(void* const* d_in, const int* in_sizes, int n_in,
                              void* d_out, int out_size, void* d_ws, size_t ws_size,
                              hipStream_t stream) {
    const float*    inputs  = (const float*)d_in[0];
    const unsigned* adjw    = (const unsigned*)d_in[1];
    const float*    op_emb  = (const float*)d_in[2];
    const float*    weight  = (const float*)d_in[3];
    const float*    attn_w  = (const float*)d_in[4];
    const float*    attn_b  = (const float*)d_in[5];
    const float*    self_op = (const float*)d_in[6];
    float* out = (float*)d_out;
    float2* S2 = (float2*)d_ws;  // fragment-layout support, 3,145,728 bytes

    support_kernel<<<(B_ * N_) / 16, 256, 0, stream>>>(inputs, weight, S2);
    // V1 probe: identical structure, no op_emb stream; its out-writes are fully
    // overwritten by the real kernel below (same stream, ordered).
    fused_probe<<<B_ * N_, 256, 0, stream>>>(op_emb, adjw, attn_w, attn_b, self_op,
                                             S2, out);
    // V0 real (last): produces the validated output.
    fused_kernel<<<B_ * N_, 256, 0, stream>>>(op_emb, adjw, attn_w, attn_b, self_op,
                                              S2, out);
}

// Round 13
// 74.967 us; speedup vs baseline: 1.8625x; 1.6884x over previous
//
#include <hip/hip_runtime.h>
#include <hip/hip_bf16.h>

// DenseGraphSimpleOpEdgeFlow — R13.
// R12 ablation: structure ~40us, op_emb stream +42us, serialized. VGPR_Count=56 => compiler
// re-serialized the staging loads (ld[5] round-trips) to cut register pressure; that defeated
// every source-level prefetch (R4/R6). Fix: global_load_lds stages the raw fp32 tile (18KB,
// contiguous, wave-uniform LDS dest + lane*16) -- fire-and-forget, zero VGPRs, full MLP.
// A conflict-free LDS pass converts fp32->bf16 into the XOR-swizzled Atile (diagonal row
// substituted with self_op there). Also: S2 re-indexed so sfrag reads are WAVE-contiguous
// (64 lanes x 8B = 512B per instr vs 64 scattered lines before). Keeps R7 mask-fold
// (d=48 column: off in {+126,-126,0}; attn = rcp(1+exp2(acc))), bias in MFMA C-init.
// Requires ws_size >= 64*96*128*4 = 3,145,728 bytes (S2 fragment-layout support scratch).

#define B_ 64
#define N_ 96
#define F_ 128
#define D_ 48

typedef __attribute__((ext_vector_type(8))) short short8;
typedef __attribute__((ext_vector_type(4))) float f32x4;

#if __has_builtin(__builtin_amdgcn_exp2f)
#define EXP2(x) __builtin_amdgcn_exp2f(x)
#else
#define EXP2(x) exp2f(x)
#endif

__device__ __forceinline__ void gload_lds16(const void* g, void* l) {
    __builtin_amdgcn_global_load_lds(
        (const __attribute__((address_space(1))) void*)g,
        (__attribute__((address_space(3))) void*)l, 16, 0, 0);
}

// S2 layout (wave-contiguous reads): float2 index (((b*6 + mt)*4 + r)*4 + lg)*64 + fbp
__device__ __forceinline__ size_t s2i(int b, int mt, int r, int lg, int fbp) {
    return ((((size_t)b * 6 + mt) * 4 + r) * 4 + lg) * 64 + fbp;
}

__device__ __forceinline__ unsigned bfbits(float x) {
    union { __hip_bfloat16 h; unsigned short u; } cv;
    cv.h = __float2bfloat16(x);
    return (unsigned)cv.u;
}

// ---------------- Kernel 1: support = inputs @ weight, written in S2 fragment layout ----------------
__global__ __launch_bounds__(256, 4) void support_kernel(
    const float* __restrict__ inputs, const float* __restrict__ weight,
    float2* __restrict__ S2)
{
    __shared__ float in_lds[16 * F_];
    const int tid = threadIdx.x;
    const int row0 = blockIdx.x * 16;
    ((float4*)in_lds)[tid]       = ((const float4*)(inputs + (size_t)row0 * F_))[tid];
    ((float4*)in_lds)[tid + 256] = ((const float4*)(inputs + (size_t)row0 * F_))[tid + 256];
    __syncthreads();
    const int rl = tid >> 4, f0 = (tid & 15) * 8;
    float acc[8] = {0.f,0.f,0.f,0.f,0.f,0.f,0.f,0.f};
    #pragma unroll 4
    for (int k = 0; k < F_; ++k) {
        const float a = in_lds[rl * F_ + k];
        const float4 w0 = *(const float4*)(weight + k * F_ + f0);
        const float4 w1 = *(const float4*)(weight + k * F_ + f0 + 4);
        acc[0] += a * w0.x; acc[1] += a * w0.y; acc[2] += a * w0.z; acc[3] += a * w0.w;
        acc[4] += a * w1.x; acc[5] += a * w1.y; acc[6] += a * w1.z; acc[7] += a * w1.w;
    }
    const int R = row0 + rl;
    const int b = R / N_, j = R - b * N_;
    const int mt = j >> 4, lg = (j >> 2) & 3, r = j & 3;
    #pragma unroll
    for (int q = 0; q < 4; ++q) {
        const int fbp = (f0 >> 1) + q;   // f-pair index
        S2[s2i(b, mt, r, lg, fbp)] = make_float2(acc[2 * q], acc[2 * q + 1]);
    }
}

// ---------------- Kernel 2: fused attn-GEMM + mask + weighted reduce + residual ----------------
// One block per (b,i); 4 waves; wave w owns f = w*32 + (lane&15)*2 + t.
// MFMA 16x16x32 k-slot fill d = ks*32 + (lane>>4)*8 + e, identical for A and B (physical-k
// permutation cancels). C/D (HW-verified): col = lane&15 (-> f-pair), row = (lane>>4)*4+reg (-> j).
__global__ __launch_bounds__(256, 2) void fused_kernel(
    const float* __restrict__ op_emb,
    const unsigned* __restrict__ adjw,      // raw 32-bit view of adj (int32 or int64)
    const float* __restrict__ attn_w,
    const float* __restrict__ attn_b,
    const float* __restrict__ self_op,
    const float2* __restrict__ S2,
    float* __restrict__ out)
{
    __shared__ __align__(16) float AtileF32[N_ * D_];        // 18,432 B: raw fp32 tile (linear)
    __shared__ __align__(16) unsigned short Atile[N_ * 64];  // 12,288 B: bf16, d=48 mask slot

    const int tid  = threadIdx.x;
    const int lane = tid & 63;
    const int wv   = tid >> 6;
    const int lg   = lane >> 4;
    const int lm   = lane & 15;
    const int fb   = wv * 32 + lm * 2;
    const int fbp  = wv * 16 + lm;

    const int blk = blockIdx.x;
    const int b   = blk / N_;
    const int i   = blk - b * N_;
    const size_t rb = (size_t)(b * N_ + i) * N_;
    const float* src = op_emb + rb * D_;      // 18,432 contiguous bytes

    const float kNL2E = -1.44269504088896f;

    // ---- stream: raw tile -> LDS, fire-and-forget (no VGPR round-trip) ----
    // 18 chunks of 1KB; wave wv takes chunks wv, wv+4, ... (LDS dest wave-uniform + lane*16).
    {
        const char* gbase = (const char*)src;
        char* lbase = (char*)AtileF32;
        for (int c = wv; c < 18; c += 4)
            gload_lds16(gbase + c * 1024 + lane * 16, lbase + c * 1024);
    }

    // --- adj dtype sniff + row load (overlaps the stream) ---
    const unsigned probe = adjw[2 * lane + 1];
    const bool use32 = __any(probe != 0);
    int araw = 0;
    if (tid < N_) {
        const size_t idx = rb + tid;
        araw = use32 ? (int)adjw[idx] : (int)adjw[2 * idx];
        araw += (tid == i) ? 1 : 0;
    }

    // --- B fragments (attn_w pre-scaled by -log2e; d==48 -> 1.0) + bias ---
    short8 bfrag[2][2];
    float  bbias[2];
    {
        const float2 bb = *(const float2*)(attn_b + fb);
        bbias[0] = bb.x * kNL2E;
        bbias[1] = bb.y * kNL2E;
        #pragma unroll
        for (int ks = 0; ks < 2; ++ks) {
            short8 v0, v1;
            #pragma unroll
            for (int e = 0; e < 8; ++e) {
                const int d = ks * 32 + lg * 8 + e;
                if (d < D_) {
                    const float2 w = *(const float2*)(attn_w + d * F_ + fb);
                    v0[e] = (short)bfbits(w.x * kNL2E);
                    v1[e] = (short)bfbits(w.y * kNL2E);
                } else {
                    const unsigned one = (d == D_) ? bfbits(1.0f) : 0u;
                    v0[e] = (short)one;
                    v1[e] = (short)one;
                }
            }
            bfrag[0][ks] = v0;
            bfrag[1][ks] = v1;
        }
    }

    // --- support fragments: 24 wave-contiguous float2 loads (512B/instr) ---
    float2 sfrag[6][4];
    #pragma unroll
    for (int mt = 0; mt < 6; ++mt)
        #pragma unroll
        for (int r = 0; r < 4; ++r)
            sfrag[mt][r] = S2[s2i(b, mt, r, lg, fbp)];

    // --- zero the k-pad d in [50,64): bytes 100..127 per row ---
    for (int v = tid; v < N_ * 7; v += 256) {
        const int j = v / 7, q = v - 7 * j;
        const int byte = j * 128 + ((100 + q * 4) ^ ((j & 7) << 4));
        *(unsigned*)((char*)Atile + byte) = 0u;
    }

    __syncthreads();   // drains global_load_lds (vmcnt) + LDS writes

    // ---- convert pass: linear fp32 LDS -> bf16 swizzled Atile; row i <- self_op ----
    #pragma unroll
    for (int s = 0; s < 5; ++s) {
        const int w = tid + s * 256;
        if (w < N_ * 12) {
            const int j = w / 12, c = w - 12 * j;
            float4 p;
            if (j == i) p = *(const float4*)(self_op + c * 4);
            else        p = *(const float4*)((const char*)AtileF32 + 16 * w);
            const int byte = j * 128 + ((c * 8) ^ ((j & 7) << 4));
            *(uint2*)((char*)Atile + byte) =
                make_uint2(bfbits(p.x) | (bfbits(p.y) << 16),
                           bfbits(p.z) | (bfbits(p.w) << 16));
        }
    }
    if (tid < N_) {
        // mask slot d=48: a'==0 -> +126 (attn 0 via exp2 saturation), a'==1 -> -126, else 0
        const float off = (araw == 0) ? 126.f : ((araw == 1) ? -126.f : 0.f);
        const int byte = tid * 128 + (96 ^ ((tid & 7) << 4));
        *(unsigned*)((char*)Atile + byte) = bfbits(off);
    }
    __syncthreads();

    // ---- compute: 6 j-slabs; attn = rcp(1 + exp2(acc)) with mask folded into acc ----
    float osum0 = 0.f, osum1 = 0.f;
    #pragma unroll
    for (int mt = 0; mt < 6; ++mt) {
        const int jr  = mt * 16 + lm;
        const int swz = (lm & 7) << 4;
        const char* base = (const char*)Atile + jr * 128;
        const short8 a0 = *(const short8*)(base + (( 0 + lg * 16) ^ swz));
        const short8 a1 = *(const short8*)(base + ((64 + lg * 16) ^ swz));
        f32x4 c0 = (f32x4){bbias[0], bbias[0], bbias[0], bbias[0]};
        f32x4 c1 = (f32x4){bbias[1], bbias[1], bbias[1], bbias[1]};
        c0 = __builtin_amdgcn_mfma_f32_16x16x32_bf16(a0, bfrag[0][0], c0, 0, 0, 0);
        c0 = __builtin_amdgcn_mfma_f32_16x16x32_bf16(a1, bfrag[0][1], c0, 0, 0, 0);
        c1 = __builtin_amdgcn_mfma_f32_16x16x32_bf16(a0, bfrag[1][0], c1, 0, 0, 0);
        c1 = __builtin_amdgcn_mfma_f32_16x16x32_bf16(a1, bfrag[1][1], c1, 0, 0, 0);
        #pragma unroll
        for (int r = 0; r < 4; ++r) {
            const float s0 = __builtin_amdgcn_rcpf(1.f + EXP2(c0[r]));
            const float s1 = __builtin_amdgcn_rcpf(1.f + EXP2(c1[r]));
            osum0 = __builtin_fmaf(s0, sfrag[mt][r].x, osum0);
            osum1 = __builtin_fmaf(s1, sfrag[mt][r].y, osum1);
        }
    }

    // ---- reduce over the 4 lg j-subsets; lanes 0..15 add residual and store ----
    osum0 += __shfl_xor(osum0, 16);
    osum0 += __shfl_xor(osum0, 32);
    osum1 += __shfl_xor(osum1, 16);
    osum1 += __shfl_xor(osum1, 32);
    if (lg == 0) {
        const float2 sr = S2[s2i(b, i >> 4, i & 3, (i >> 2) & 3, fbp)];
        float2 o;
        o.x = osum0 + sr.x;
        o.y = osum1 + sr.y;
        *(float2*)(out + (size_t)(b * N_ + i) * F_ + fb) = o;
    }
}

extern "C" void kernel_launch(void* const* d_in, const int* in_sizes, int n_in,
                              void* d_out, int out_size, void* d_ws, size_t ws_size,
                              hipStream_t stream) {
    const float*    inputs  = (const float*)d_in[0];
    const unsigned* adjw    = (const unsigned*)d_in[1];
    const float*    op_emb  = (const float*)d_in[2];
    const float*    weight  = (const float*)d_in[3];
    const float*    attn_w  = (const float*)d_in[4];
    const float*    attn_b  = (const float*)d_in[5];
    const float*    self_op = (const float*)d_in[6];
    float* out = (float*)d_out;
    float2* S2 = (float2*)d_ws;  // fragment-layout support, 3,145,728 bytes

    support_kernel<<<(B_ * N_) / 16, 256, 0, stream>>>(inputs, weight, S2);
    fused_kernel<<<B_ * N_, 256, 0, stream>>>(op_emb, adjw, attn_w, attn_b, self_op,
                                              S2, out);
}

// Round 14
// 65.627 us; speedup vs baseline: 2.1275x; 1.1423x over previous
//
#include <hip/hip_runtime.h>
#include <hip/hip_bf16.h>

// DenseGraphSimpleOpEdgeFlow — R14: minimum-2-phase pipeline (T3/T4 recipe).
// R12/R13 ablation: no-stream structure = 40us; stream adds +36us INDEPENDENT of residency
// (HBM vs L3 identical) => pure latency exposure: __syncthreads after staging drains vmcnt(0)
// per tile (the m97 barrier-drain stall), 6144x. Fix: G=8 tiles/block (768 blocks = 3/CU),
// double fp32 LDS buffer via global_load_lds, RAW s_barrier + manual s_waitcnt so next-tile
// loads stay in flight across barriers. Per tile: {issue g+1}{convert cur->Atile}lgkm(0)+bar
// {MFMA+epilogue+store} vmcnt(1)+bar. Preamble (sfrag/bfrag/pads) amortized 8x.
// Keeps: 49th-K mask fold (d48 col, attn = rcp(1+exp2(acc))), bias in MFMA C-init,
// wave-contiguous S2 layout, XOR-swizzled bf16 Atile.
// Requires ws_size >= 64*96*128*4 = 3,145,728 bytes (S2 fragment-layout support scratch).

#define B_ 64
#define N_ 96
#define F_ 128
#define D_ 48
#define G_ 8
#define NGRP (N_ / G_)   // 12 groups per b -> grid = 64*12 = 768 blocks = 3/CU

typedef __attribute__((ext_vector_type(8))) short short8;
typedef __attribute__((ext_vector_type(4))) float f32x4;

#if __has_builtin(__builtin_amdgcn_exp2f)
#define EXP2(x) __builtin_amdgcn_exp2f(x)
#else
#define EXP2(x) exp2f(x)
#endif

__device__ __forceinline__ void gload_lds16(const void* g, void* l) {
    __builtin_amdgcn_global_load_lds(
        (const __attribute__((address_space(1))) void*)g,
        (__attribute__((address_space(3))) void*)l, 16, 0, 0);
}

// S2 layout (wave-contiguous reads): float2 index (((b*6 + mt)*4 + r)*4 + lg)*64 + fbp
__device__ __forceinline__ size_t s2i(int b, int mt, int r, int lg, int fbp) {
    return ((((size_t)b * 6 + mt) * 4 + r) * 4 + lg) * 64 + fbp;
}

__device__ __forceinline__ unsigned bfbits(float x) {
    union { __hip_bfloat16 h; unsigned short u; } cv;
    cv.h = __float2bfloat16(x);
    return (unsigned)cv.u;
}

// ---------------- Kernel 1: support = inputs @ weight, written in S2 fragment layout ----------------
__global__ __launch_bounds__(256, 4) void support_kernel(
    const float* __restrict__ inputs, const float* __restrict__ weight,
    float2* __restrict__ S2)
{
    __shared__ float in_lds[16 * F_];
    const int tid = threadIdx.x;
    const int row0 = blockIdx.x * 16;
    ((float4*)in_lds)[tid]       = ((const float4*)(inputs + (size_t)row0 * F_))[tid];
    ((float4*)in_lds)[tid + 256] = ((const float4*)(inputs + (size_t)row0 * F_))[tid + 256];
    __syncthreads();
    const int rl = tid >> 4, f0 = (tid & 15) * 8;
    float acc[8] = {0.f,0.f,0.f,0.f,0.f,0.f,0.f,0.f};
    #pragma unroll 4
    for (int k = 0; k < F_; ++k) {
        const float a = in_lds[rl * F_ + k];
        const float4 w0 = *(const float4*)(weight + k * F_ + f0);
        const float4 w1 = *(const float4*)(weight + k * F_ + f0 + 4);
        acc[0] += a * w0.x; acc[1] += a * w0.y; acc[2] += a * w0.z; acc[3] += a * w0.w;
        acc[4] += a * w1.x; acc[5] += a * w1.y; acc[6] += a * w1.z; acc[7] += a * w1.w;
    }
    const int R = row0 + rl;
    const int b = R / N_, j = R - b * N_;
    const int mt = j >> 4, lg = (j >> 2) & 3, r = j & 3;
    #pragma unroll
    for (int q = 0; q < 4; ++q) {
        const int fbp = (f0 >> 1) + q;   // f-pair index
        S2[s2i(b, mt, r, lg, fbp)] = make_float2(acc[2 * q], acc[2 * q + 1]);
    }
}

// ---------------- Kernel 2: fused attn-GEMM, software-pipelined over 8 tiles ----------------
// 4 waves; wave w owns f = w*32 + (lane&15)*2 + t. MFMA 16x16x32 k-slot fill
// d = ks*32 + (lane>>4)*8 + e, identical for A and B (physical-k permutation cancels).
// C/D (HW-verified): col = lane&15 (-> f-pair), row = (lane>>4)*4 + reg (-> j).
__global__ __launch_bounds__(256, 2) void fused_kernel(
    const float* __restrict__ op_emb,
    const unsigned* __restrict__ adjw,      // raw 32-bit view of adj (int32 or int64)
    const float* __restrict__ attn_w,
    const float* __restrict__ attn_b,
    const float* __restrict__ self_op,
    const float2* __restrict__ S2,
    float* __restrict__ out)
{
    __shared__ __align__(16) float F32buf[2][N_ * D_];       // 2 x 18,432 B raw fp32 tiles
    __shared__ __align__(16) unsigned short Atile[N_ * 64];  // 12,288 B bf16; d=48 mask slot

    const int tid  = threadIdx.x;
    const int lane = tid & 63;
    const int wv   = tid >> 6;
    const int lg   = lane >> 4;
    const int lm   = lane & 15;
    const int fb   = wv * 32 + lm * 2;
    const int fbp  = wv * 16 + lm;

    const int blk = blockIdx.x;
    const int b   = blk / NGRP;
    const int grp = blk - b * NGRP;
    const int i0  = grp * G_;

    const float kNL2E = -1.44269504088896f;

    // --- adj dtype sniff: int64 little-endian has all-zero high words (values 0..4) ---
    const unsigned probe = adjw[2 * lane + 1];
    const bool use32 = __any(probe != 0);

    // issue the 18 x 1KB direct-to-LDS copies for tile i -> F32buf[pb] (fire-and-forget)
    auto issue_tile = [&](int i, int pb) {
        const char* gbase = (const char*)(op_emb + (size_t)(b * N_ + i) * N_ * D_);
        char* lbase = (char*)(&F32buf[pb][0]);
        #pragma unroll
        for (int c0 = 0; c0 < 5; ++c0) {
            const int c = wv + 4 * c0;
            if (c < 18) gload_lds16(gbase + c * 1024 + lane * 16, lbase + c * 1024);
        }
    };
    auto load_adj = [&](int i) -> int {
        int a = 0;
        if (tid < N_) {
            const size_t idx = (size_t)(b * N_ + i) * N_ + tid;
            a = use32 ? (int)adjw[idx] : (int)adjw[2 * idx];
            a += (tid == i) ? 1 : 0;
        }
        return a;
    };

    // ---- prologue: issue tile 0 + adj row 0 (latency overlaps the preamble below) ----
    issue_tile(i0, 0);
    int adjreg = load_adj(i0);

    // --- B fragments (attn_w pre-scaled by -log2e; d==48 -> 1.0) + bias ---
    short8 bfrag[2][2];
    float  bbias[2];
    {
        const float2 bb = *(const float2*)(attn_b + fb);
        bbias[0] = bb.x * kNL2E;
        bbias[1] = bb.y * kNL2E;
        #pragma unroll
        for (int ks = 0; ks < 2; ++ks) {
            short8 v0, v1;
            #pragma unroll
            for (int e = 0; e < 8; ++e) {
                const int d = ks * 32 + lg * 8 + e;
                if (d < D_) {
                    const float2 w = *(const float2*)(attn_w + d * F_ + fb);
                    v0[e] = (short)bfbits(w.x * kNL2E);
                    v1[e] = (short)bfbits(w.y * kNL2E);
                } else {
                    const unsigned one = (d == D_) ? bfbits(1.0f) : 0u;
                    v0[e] = (short)one;
                    v1[e] = (short)one;
                }
            }
            bfrag[0][ks] = v0;
            bfrag[1][ks] = v1;
        }
    }

    // --- support fragments: 24 wave-contiguous float2 loads, b-invariant for all 8 tiles ---
    float2 sfrag[6][4];
    #pragma unroll
    for (int mt = 0; mt < 6; ++mt)
        #pragma unroll
        for (int r = 0; r < 4; ++r)
            sfrag[mt][r] = S2[s2i(b, mt, r, lg, fbp)];

    // --- zero Atile k-pad d in [50,64) once per block (convert only writes d 0..49) ---
    for (int v = tid; v < N_ * 7; v += 256) {
        const int j = v / 7, q = v - 7 * j;
        const int byte = j * 128 + ((100 + q * 4) ^ ((j & 7) << 4));
        *(unsigned*)((char*)Atile + byte) = 0u;
    }

    __syncthreads();   // full drain: tile-0 loads + pad writes visible (once per block)

    #pragma unroll 1
    for (int g = 0; g < G_; ++g) {
        const int cur = g & 1;
        const int i = i0 + g;

        // ---- 1. issue next tile's loads (stay in flight across both barriers) ----
        int adjnext = 0;
        if (g + 1 < G_) {
            issue_tile(i + 1, cur ^ 1);
            adjnext = load_adj(i + 1);
        }

        // ---- 2. convert F32buf[cur] -> bf16 swizzled Atile; row i <- self_op; d48 <- off ----
        #pragma unroll
        for (int s = 0; s < 5; ++s) {
            const int w = tid + s * 256;
            if (w < N_ * 12) {
                const int j = w / 12, c = w - 12 * j;
                float4 p;
                if (j == i) p = *(const float4*)(self_op + c * 4);
                else        p = *(const float4*)((const char*)(&F32buf[cur][0]) + 16 * w);
                const int byte = j * 128 + ((c * 8) ^ ((j & 7) << 4));
                *(uint2*)((char*)Atile + byte) =
                    make_uint2(bfbits(p.x) | (bfbits(p.y) << 16),
                               bfbits(p.z) | (bfbits(p.w) << 16));
            }
        }
        if (tid < N_) {
            // mask slot d=48: a'==0 -> +126 (attn 0 via exp2 saturation), a'==1 -> -126, else 0
            const float off = (adjreg == 0) ? 126.f : ((adjreg == 1) ? -126.f : 0.f);
            const int byte = tid * 128 + (96 ^ ((tid & 7) << 4));
            *(unsigned*)((char*)Atile + byte) = bfbits(off);
        }
        asm volatile("s_waitcnt lgkmcnt(0)" ::: "memory");  // LDS writes visible
        __builtin_amdgcn_s_barrier();                       // (no vmcnt drain!)

        // ---- 3. compute: 6 j-slabs; attn = rcp(1 + exp2(acc)); store ----
        float osum0 = 0.f, osum1 = 0.f;
        #pragma unroll
        for (int mt = 0; mt < 6; ++mt) {
            const int jr  = mt * 16 + lm;
            const int swz = (lm & 7) << 4;
            const char* base = (const char*)Atile + jr * 128;
            const short8 a0 = *(const short8*)(base + (( 0 + lg * 16) ^ swz));
            const short8 a1 = *(const short8*)(base + ((64 + lg * 16) ^ swz));
            f32x4 c0 = (f32x4){bbias[0], bbias[0], bbias[0], bbias[0]};
            f32x4 c1 = (f32x4){bbias[1], bbias[1], bbias[1], bbias[1]};
            c0 = __builtin_amdgcn_mfma_f32_16x16x32_bf16(a0, bfrag[0][0], c0, 0, 0, 0);
            c0 = __builtin_amdgcn_mfma_f32_16x16x32_bf16(a1, bfrag[0][1], c0, 0, 0, 0);
            c1 = __builtin_amdgcn_mfma_f32_16x16x32_bf16(a0, bfrag[1][0], c1, 0, 0, 0);
            c1 = __builtin_amdgcn_mfma_f32_16x16x32_bf16(a1, bfrag[1][1], c1, 0, 0, 0);
            #pragma unroll
            for (int r = 0; r < 4; ++r) {
                const float s0 = __builtin_amdgcn_rcpf(1.f + EXP2(c0[r]));
                const float s1 = __builtin_amdgcn_rcpf(1.f + EXP2(c1[r]));
                osum0 = __builtin_fmaf(s0, sfrag[mt][r].x, osum0);
                osum1 = __builtin_fmaf(s1, sfrag[mt][r].y, osum1);
            }
        }
        osum0 += __shfl_xor(osum0, 16);
        osum0 += __shfl_xor(osum0, 32);
        osum1 += __shfl_xor(osum1, 16);
        osum1 += __shfl_xor(osum1, 32);
        if (lg == 0) {
            const float2 sr = S2[s2i(b, i >> 4, i & 3, (i >> 2) & 3, fbp)];
            float2 o;
            o.x = osum0 + sr.x;
            o.y = osum1 + sr.y;
            *(float2*)(out + (size_t)(b * N_ + i) * F_ + fb) = o;
        }

        // ---- 4. wait next-tile loads (all but our newest store), then release Atile ----
        asm volatile("s_waitcnt vmcnt(1)" ::: "memory");
        __builtin_amdgcn_s_barrier();
        adjreg = adjnext;
    }
}

extern "C" void kernel_launch(void* const* d_in, const int* in_sizes, int n_in,
                              void* d_out, int out_size, void* d_ws, size_t ws_size,
                              hipStream_t stream) {
    const float*    inputs  = (const float*)d_in[0];
    const unsigned* adjw    = (const unsigned*)d_in[1];
    const float*    op_emb  = (const float*)d_in[2];
    const float*    weight  = (const float*)d_in[3];
    const float*    attn_w  = (const float*)d_in[4];
    const float*    attn_b  = (const float*)d_in[5];
    const float*    self_op = (const float*)d_in[6];
    float* out = (float*)d_out;
    float2* S2 = (float2*)d_ws;  // fragment-layout support, 3,145,728 bytes

    support_kernel<<<(B_ * N_) / 16, 256, 0, stream>>>(inputs, weight, S2);
    fused_kernel<<<B_ * NGRP, 256, 0, stream>>>(op_emb, adjw, attn_w, attn_b, self_op,
                                                S2, out);
}

// Round 15
// 61.476 us; speedup vs baseline: 2.2712x; 1.0675x over previous
//
#include <hip/hip_runtime.h>
#include <hip/hip_bf16.h>

// DenseGraphSimpleOpEdgeFlow — R15: R14's pipeline + 2x waves per CU.
// R14 (2-phase pipeline, raw barriers, global_load_lds dbuf) improved 76->70us but occupancy
// fell to 15.6% (2 phase-aligned 4-wave blocks/CU): waves run CPI~4-5 with nothing to cover
// latency. This round: 512-thread blocks (8 waves), (512,4) -> VGPR cap 128 (body ~90, no
// spill; NOT 1024 threads -- R11 showed that caps at 64 and spills). Tile split (wf=f-slice)
// x (wj=mt-half): per-wave work halves, cross-half reduce via small LDS partial buffer.
// Per-tile: {issue g+1}{convert}{lgkm0+bar}{MFMA+sigmoid, wj1 writes partial}{lgkm0+bar}
// {wj0 adds partial + residual, stores}{vmcnt0+bar}. vmcnt(0) because wj=1 waves issue no
// store (R14's vmcnt(1) relied on the store being the newest vmem op per wave).
// Keeps: 49th-K mask fold (d48; attn = rcp(1+exp2(acc))), bias in C-init, S2 frag layout.
// Requires ws_size >= 64*96*128*4 = 3,145,728 bytes (S2 scratch).

#define B_ 64
#define N_ 96
#define F_ 128
#define D_ 48
#define G_ 12
#define NGRP (N_ / G_)   // 8 groups per b -> grid = 64*8 = 512 blocks = 2/CU

typedef __attribute__((ext_vector_type(8))) short short8;
typedef __attribute__((ext_vector_type(4))) float f32x4;

#if __has_builtin(__builtin_amdgcn_exp2f)
#define EXP2(x) __builtin_amdgcn_exp2f(x)
#else
#define EXP2(x) exp2f(x)
#endif

__device__ __forceinline__ void gload_lds16(const void* g, void* l) {
    __builtin_amdgcn_global_load_lds(
        (const __attribute__((address_space(1))) void*)g,
        (__attribute__((address_space(3))) void*)l, 16, 0, 0);
}

// S2 layout (wave-contiguous reads): float2 index (((b*6 + mt)*4 + r)*4 + lg)*64 + fbp
__device__ __forceinline__ size_t s2i(int b, int mt, int r, int lg, int fbp) {
    return ((((size_t)b * 6 + mt) * 4 + r) * 4 + lg) * 64 + fbp;
}

__device__ __forceinline__ unsigned bfbits(float x) {
    union { __hip_bfloat16 h; unsigned short u; } cv;
    cv.h = __float2bfloat16(x);
    return (unsigned)cv.u;
}

// ---------------- Kernel 1: support = inputs @ weight, written in S2 fragment layout ----------------
__global__ __launch_bounds__(256, 4) void support_kernel(
    const float* __restrict__ inputs, const float* __restrict__ weight,
    float2* __restrict__ S2)
{
    __shared__ float in_lds[16 * F_];
    const int tid = threadIdx.x;
    const int row0 = blockIdx.x * 16;
    ((float4*)in_lds)[tid]       = ((const float4*)(inputs + (size_t)row0 * F_))[tid];
    ((float4*)in_lds)[tid + 256] = ((const float4*)(inputs + (size_t)row0 * F_))[tid + 256];
    __syncthreads();
    const int rl = tid >> 4, f0 = (tid & 15) * 8;
    float acc[8] = {0.f,0.f,0.f,0.f,0.f,0.f,0.f,0.f};
    #pragma unroll 4
    for (int k = 0; k < F_; ++k) {
        const float a = in_lds[rl * F_ + k];
        const float4 w0 = *(const float4*)(weight + k * F_ + f0);
        const float4 w1 = *(const float4*)(weight + k * F_ + f0 + 4);
        acc[0] += a * w0.x; acc[1] += a * w0.y; acc[2] += a * w0.z; acc[3] += a * w0.w;
        acc[4] += a * w1.x; acc[5] += a * w1.y; acc[6] += a * w1.z; acc[7] += a * w1.w;
    }
    const int R = row0 + rl;
    const int b = R / N_, j = R - b * N_;
    const int mt = j >> 4, lg = (j >> 2) & 3, r = j & 3;
    #pragma unroll
    for (int q = 0; q < 4; ++q) {
        const int fbp = (f0 >> 1) + q;   // f-pair index
        S2[s2i(b, mt, r, lg, fbp)] = make_float2(acc[2 * q], acc[2 * q + 1]);
    }
}

// ---------------- Kernel 2: fused attn-GEMM, pipelined, 8 waves = (4 f-slices) x (2 mt-halves) ----------------
// MFMA 16x16x32 k-slot fill d = ks*32 + (lane>>4)*8 + e, identical for A and B (physical-k
// permutation cancels). C/D (HW-verified): col = lane&15 (-> f-pair), row = (lane>>4)*4+reg (-> j).
__global__ __launch_bounds__(512, 4) void fused_kernel(
    const float* __restrict__ op_emb,
    const unsigned* __restrict__ adjw,      // raw 32-bit view of adj (int32 or int64)
    const float* __restrict__ attn_w,
    const float* __restrict__ attn_b,
    const float* __restrict__ self_op,
    const float2* __restrict__ S2,
    float* __restrict__ out)
{
    __shared__ __align__(16) float F32buf[2][N_ * D_];       // 2 x 18,432 B raw fp32 tiles
    __shared__ __align__(16) unsigned short Atile[N_ * 64];  // 12,288 B bf16; d=48 mask slot
    __shared__ __align__(8)  float2 Ppart[4][16];            // wj=1 partial sums (wf, lm)

    const int tid  = threadIdx.x;
    const int lane = tid & 63;
    const int wid  = tid >> 6;      // wave 0..7
    const int wf   = wid & 3;       // f-slice
    const int wj   = wid >> 2;      // mt-half: mt in [3*wj, 3*wj+3)
    const int lg   = lane >> 4;
    const int lm   = lane & 15;
    const int fb   = wf * 32 + lm * 2;
    const int fbp  = wf * 16 + lm;

    const int blk = blockIdx.x;
    const int b   = blk / NGRP;
    const int grp = blk - b * NGRP;
    const int i0  = grp * G_;

    const float kNL2E = -1.44269504088896f;

    // --- adj dtype sniff: int64 little-endian has all-zero high words (values 0..4) ---
    const unsigned probe = adjw[2 * lane + 1];
    const bool use32 = __any(probe != 0);

    // issue the 18 x 1KB direct-to-LDS copies for tile i -> F32buf[pb] (fire-and-forget)
    auto issue_tile = [&](int i, int pb) {
        const char* gbase = (const char*)(op_emb + (size_t)(b * N_ + i) * N_ * D_);
        char* lbase = (char*)(&F32buf[pb][0]);
        #pragma unroll
        for (int c0 = 0; c0 < 3; ++c0) {
            const int c = wid + 8 * c0;
            if (c < 18) gload_lds16(gbase + c * 1024 + lane * 16, lbase + c * 1024);
        }
    };
    auto load_adj = [&](int i) -> int {
        int a = 0;
        if (tid < N_) {
            const size_t idx = (size_t)(b * N_ + i) * N_ + tid;
            a = use32 ? (int)adjw[idx] : (int)adjw[2 * idx];
            a += (tid == i) ? 1 : 0;
        }
        return a;
    };

    // ---- prologue: issue tile 0 + adj row 0 (latency overlaps the preamble below) ----
    issue_tile(i0, 0);
    int adjreg = load_adj(i0);

    // --- B fragments (attn_w pre-scaled by -log2e; d==48 -> 1.0) + bias ---
    short8 bfrag[2][2];
    float  bbias[2];
    {
        const float2 bb = *(const float2*)(attn_b + fb);
        bbias[0] = bb.x * kNL2E;
        bbias[1] = bb.y * kNL2E;
        #pragma unroll
        for (int ks = 0; ks < 2; ++ks) {
            short8 v0, v1;
            #pragma unroll
            for (int e = 0; e < 8; ++e) {
                const int d = ks * 32 + lg * 8 + e;
                if (d < D_) {
                    const float2 w = *(const float2*)(attn_w + d * F_ + fb);
                    v0[e] = (short)bfbits(w.x * kNL2E);
                    v1[e] = (short)bfbits(w.y * kNL2E);
                } else {
                    const unsigned one = (d == D_) ? bfbits(1.0f) : 0u;
                    v0[e] = (short)one;
                    v1[e] = (short)one;
                }
            }
            bfrag[0][ks] = v0;
            bfrag[1][ks] = v1;
        }
    }

    // --- support fragments for THIS wave's mt-half: 12 wave-segment float2 loads ---
    float2 sfrag[3][4];
    #pragma unroll
    for (int s = 0; s < 3; ++s)
        #pragma unroll
        for (int r = 0; r < 4; ++r)
            sfrag[s][r] = S2[s2i(b, 3 * wj + s, r, lg, fbp)];

    // --- zero Atile k-pad d in [50,64) once per block ---
    for (int v = tid; v < N_ * 7; v += 512) {
        const int j = v / 7, q = v - 7 * j;
        const int byte = j * 128 + ((100 + q * 4) ^ ((j & 7) << 4));
        *(unsigned*)((char*)Atile + byte) = 0u;
    }

    __syncthreads();   // full drain once per block: tile-0 loads + pad writes visible

    #pragma unroll 1
    for (int g = 0; g < G_; ++g) {
        const int cur = g & 1;
        const int i = i0 + g;

        // ---- 1. issue next tile's loads (stay in flight across the barriers) ----
        int adjnext = 0;
        if (g + 1 < G_) {
            issue_tile(i + 1, cur ^ 1);
            adjnext = load_adj(i + 1);
        }

        // ---- 2. convert F32buf[cur] -> bf16 swizzled Atile; row i <- self_op; d48 <- off ----
        #pragma unroll
        for (int s = 0; s < 3; ++s) {
            const int w = tid + s * 512;
            if (w < N_ * 12) {
                const int j = w / 12, c = w - 12 * j;
                float4 p;
                if (j == i) p = *(const float4*)(self_op + c * 4);
                else        p = *(const float4*)((const char*)(&F32buf[cur][0]) + 16 * w);
                const int byte = j * 128 + ((c * 8) ^ ((j & 7) << 4));
                *(uint2*)((char*)Atile + byte) =
                    make_uint2(bfbits(p.x) | (bfbits(p.y) << 16),
                               bfbits(p.z) | (bfbits(p.w) << 16));
            }
        }
        if (tid < N_) {
            // mask slot d=48: a'==0 -> +126 (attn 0 via exp2 saturation), a'==1 -> -126, else 0
            const float off = (adjreg == 0) ? 126.f : ((adjreg == 1) ? -126.f : 0.f);
            const int byte = tid * 128 + (96 ^ ((tid & 7) << 4));
            *(unsigned*)((char*)Atile + byte) = bfbits(off);
        }
        asm volatile("s_waitcnt lgkmcnt(0)" ::: "memory");  // Atile writes visible
        __builtin_amdgcn_s_barrier();                       // (no vmcnt drain)

        // ---- 3. compute: this wave's 3 mt-slabs; attn = rcp(1 + exp2(acc)) ----
        float osum0 = 0.f, osum1 = 0.f;
        #pragma unroll
        for (int s = 0; s < 3; ++s) {
            const int mt  = 3 * wj + s;
            const int jr  = mt * 16 + lm;
            const int swz = (lm & 7) << 4;
            const char* base = (const char*)Atile + jr * 128;
            const short8 a0 = *(const short8*)(base + (( 0 + lg * 16) ^ swz));
            const short8 a1 = *(const short8*)(base + ((64 + lg * 16) ^ swz));
            f32x4 c0 = (f32x4){bbias[0], bbias[0], bbias[0], bbias[0]};
            f32x4 c1 = (f32x4){bbias[1], bbias[1], bbias[1], bbias[1]};
            c0 = __builtin_amdgcn_mfma_f32_16x16x32_bf16(a0, bfrag[0][0], c0, 0, 0, 0);
            c0 = __builtin_amdgcn_mfma_f32_16x16x32_bf16(a1, bfrag[0][1], c0, 0, 0, 0);
            c1 = __builtin_amdgcn_mfma_f32_16x16x32_bf16(a0, bfrag[1][0], c1, 0, 0, 0);
            c1 = __builtin_amdgcn_mfma_f32_16x16x32_bf16(a1, bfrag[1][1], c1, 0, 0, 0);
            #pragma unroll
            for (int r = 0; r < 4; ++r) {
                const float s0 = __builtin_amdgcn_rcpf(1.f + EXP2(c0[r]));
                const float s1 = __builtin_amdgcn_rcpf(1.f + EXP2(c1[r]));
                osum0 = __builtin_fmaf(s0, sfrag[s][r].x, osum0);
                osum1 = __builtin_fmaf(s1, sfrag[s][r].y, osum1);
            }
        }
        // reduce over the 4 lg j-subsets within the wave
        osum0 += __shfl_xor(osum0, 16);
        osum0 += __shfl_xor(osum0, 32);
        osum1 += __shfl_xor(osum1, 16);
        osum1 += __shfl_xor(osum1, 32);
        // wj=1 publishes its half
        if (wj == 1 && lg == 0)
            Ppart[wf][lm] = make_float2(osum0, osum1);
        asm volatile("s_waitcnt lgkmcnt(0)" ::: "memory");
        __builtin_amdgcn_s_barrier();                       // partials ready; Atile free

        // ---- 4. wj=0 adds partner half + residual and stores ----
        if (wj == 0 && lg == 0) {
            const float2 pp = Ppart[wf][lm];
            const float2 sr = S2[s2i(b, i >> 4, i & 3, (i >> 2) & 3, fbp)];
            float2 o;
            o.x = osum0 + pp.x + sr.x;
            o.y = osum1 + pp.y + sr.y;
            *(float2*)(out + (size_t)(b * N_ + i) * F_ + fb) = o;
        }

        // ---- 5. wait next-tile loads landed, then release F32buf/Atile ----
        asm volatile("s_waitcnt vmcnt(0)" ::: "memory");
        __builtin_amdgcn_s_barrier();
        adjreg = adjnext;
    }
}

extern "C" void kernel_launch(void* const* d_in, const int* in_sizes, int n_in,
                              void* d_out, int out_size, void* d_ws, size_t ws_size,
                              hipStream_t stream) {
    const float*    inputs  = (const float*)d_in[0];
    const unsigned* adjw    = (const unsigned*)d_in[1];
    const float*    op_emb  = (const float*)d_in[2];
    const float*    weight  = (const float*)d_in[3];
    const float*    attn_w  = (const float*)d_in[4];
    const float*    attn_b  = (const float*)d_in[5];
    const float*    self_op = (const float*)d_in[6];
    float* out = (float*)d_out;
    float2* S2 = (float2*)d_ws;  // fragment-layout support, 3,145,728 bytes

    support_kernel<<<(B_ * N_) / 16, 256, 0, stream>>>(inputs, weight, S2);
    fused_kernel<<<B_ * NGRP, 512, 0, stream>>>(op_emb, adjw, attn_w, attn_b, self_op,
                                                S2, out);
}